// Round 3
// baseline (1056.189 us; speedup 1.0000x reference)
//
#include <hip/hip_runtime.h>
#include <hip/hip_bf16.h>
#include <stdint.h>

#define DIM   1024
#define NE    8
#define HID   2730
#define HPAD  2752      // stage-2 K padded to multiple of 64 (43 k-iters)
#define NTOK  8192      // B*N = 4*2048
#define CAP   8192      // max tokens per expert
#define NSLOT 16384     // NTOK * TOP_K

typedef __bf16 bf16x8 __attribute__((ext_vector_type(8)));
typedef float  floatx4 __attribute__((ext_vector_type(4)));

__device__ __forceinline__ unsigned short f2bf(float f) {
    union { float f; unsigned int u; } v; v.f = f;
    unsigned int u = v.u;
    unsigned int r = (u + 0x7fffu + ((u >> 16) & 1u)) >> 16;  // RNE
    return (unsigned short)r;
}

__device__ __forceinline__ float bf2f(unsigned short b) {
    union { unsigned int u; float f; } v; v.u = (unsigned int)b << 16;
    return v.f;
}

__device__ __forceinline__ void gl2lds16(const void* g, void* l) {
    __builtin_amdgcn_global_load_lds((const __attribute__((address_space(1))) void*)g,
                                     (__attribute__((address_space(3))) void*)l,
                                     16, 0, 0);
}

// ---------------- merged weight conversion (w1, w3, w2) ----------------
__global__ void convert_w_kernel(const float* __restrict__ w1, const float* __restrict__ w3,
                                 const float* __restrict__ w2,
                                 unsigned short* __restrict__ w1b, unsigned short* __restrict__ w3b,
                                 unsigned short* __restrict__ w2b) {
    const int HALF = (NE * HID * DIM) / 4;   // 5,591,040 float4 chunks per w1/w3
    const int W13  = 2 * HALF;               // 11,182,080
    int gid = blockIdx.x * 256 + threadIdx.x;
    if (gid < W13) {
        const float* src; unsigned short* dst; int j;
        if (gid < HALF) { src = w1; dst = w1b; j = gid; }
        else            { src = w3; dst = w3b; j = gid - HALF; }
        float4 v = ((const float4*)src)[j];
        uint2 o;
        o.x = (unsigned)f2bf(v.x) | ((unsigned)f2bf(v.y) << 16);
        o.y = (unsigned)f2bf(v.z) | ((unsigned)f2bf(v.w) << 16);
        *(uint2*)(dst + (size_t)j * 4) = o;
    } else {
        int i = gid - W13;                   // 8192 rows * 688 chunks
        int r = i / 688;
        int c = (i - r * 688) * 4;
        const float* src = w2 + r * HID;
        unsigned short q[4];
#pragma unroll
        for (int j = 0; j < 4; ++j) {
            int col = c + j;
            q[j] = (col < HID) ? f2bf(src[col]) : (unsigned short)0;  // zero pad annihilates h pad cols
        }
        uint2 o;
        o.x = (unsigned)q[0] | ((unsigned)q[1] << 16);
        o.y = (unsigned)q[2] | ((unsigned)q[3] << 16);
        *(uint2*)(w2b + (size_t)r * HPAD + c) = o;
    }
}

// ---------------- router (also emits xb = bf16(x)) ----------------
__global__ void router_kernel(const float* __restrict__ x, const float* __restrict__ gw,
                              unsigned short* __restrict__ xb,
                              int* __restrict__ toks, int* __restrict__ meta,
                              float* __restrict__ tokw,
                              int* __restrict__ counts, float* __restrict__ psum) {
    __shared__ float gws[NE * DIM];        // 32 KB
    __shared__ float pblk[4][NE];
    int t = threadIdx.x;
    for (int i = t; i < NE * DIM; i += 256) gws[i] = gw[i];
    __syncthreads();

    int wv = t >> 6, lane = t & 63;
    int tok = blockIdx.x * 4 + wv;
    const float4* x4 = (const float4*)(x + (size_t)tok * DIM);
    uint2* xbrow = (uint2*)(xb + (size_t)tok * DIM);

    float p[NE];
#pragma unroll
    for (int e = 0; e < NE; ++e) p[e] = 0.f;
#pragma unroll
    for (int c = 0; c < 4; ++c) {
        float4 xv = x4[c * 64 + lane];
        uint2 o;
        o.x = (unsigned)f2bf(xv.x) | ((unsigned)f2bf(xv.y) << 16);
        o.y = (unsigned)f2bf(xv.z) | ((unsigned)f2bf(xv.w) << 16);
        xbrow[c * 64 + lane] = o;
#pragma unroll
        for (int e = 0; e < NE; ++e) {
            float4 gv = ((const float4*)(gws + e * DIM))[c * 64 + lane];
            p[e] += xv.x * gv.x + xv.y * gv.y + xv.z * gv.z + xv.w * gv.w;
        }
    }
#pragma unroll
    for (int e = 0; e < NE; ++e)
#pragma unroll
        for (int s = 32; s; s >>= 1) p[e] += __shfl_xor(p[e], s, 64);

    if (lane == 0) {
        float mx = p[0];
#pragma unroll
        for (int e = 1; e < NE; ++e) mx = fmaxf(mx, p[e]);
        float ex[NE], s = 0.f;
#pragma unroll
        for (int e = 0; e < NE; ++e) { ex[e] = __expf(p[e] - mx); s += ex[e]; }
        float inv = 1.f / s;
        int i1 = 0, i2 = 0; float v1 = -1.f, v2 = -1.f;
#pragma unroll
        for (int e = 0; e < NE; ++e) {
            float pe = ex[e] * inv;
            pblk[wv][e] = pe;
            if (pe > v1)      { v2 = v1; i2 = i1; v1 = pe; i1 = e; }
            else if (pe > v2) { v2 = pe; i2 = e; }
        }
        float wn = 1.f / (v1 + v2);
        int p1 = atomicAdd(&counts[i1], 1);
        toks[i1 * CAP + p1] = tok;
        meta[tok * 2]     = (i1 << 16) | p1;
        tokw[tok * 2]     = v1 * wn;
        int p2 = atomicAdd(&counts[i2], 1);
        toks[i2 * CAP + p2] = tok;
        meta[tok * 2 + 1] = (i2 << 16) | p2;
        tokw[tok * 2 + 1] = v2 * wn;
    }
    __syncthreads();
    if (t < NE) {
        float s = pblk[0][t] + pblk[1][t] + pblk[2][t] + pblk[3][t];
        atomicAdd(&psum[t], s);
    }
}

__global__ void finalize_kernel(const int* __restrict__ counts, int* __restrict__ offs,
                                const float* __restrict__ psum, float* __restrict__ aux_out) {
    if (threadIdx.x == 0) {
        int off = 0;
        for (int e = 0; e < NE; ++e) { offs[e] = off; off += counts[e]; }
        float s = 0.f;
        for (int e = 0; e < NE; ++e) {
            float d = psum[e] * (1.f / NTOK) - (1.f / NE);
            s += d * d;
        }
        aux_out[0] = 0.01f * s * (1.f / NE);
    }
}

// ---------------- stage-1: h = silu(x@w1^T) * (x@w3^T), gathered rows ----------------
// Grid: x = m-blocks (innermost) so consecutive blocks share the (n0,e) B-tiles ->
// the big weight stream gets L2/LLC temporal reuse; A (16MB unique) streams.
// LDS XOR swizzle on 16B chunks kills bank conflicts (verified: 5.35e7 -> 0).
__global__ __launch_bounds__(256, 2) void gemm1_kernel(
    const unsigned short* __restrict__ xb,
    const unsigned short* __restrict__ w1b,
    const unsigned short* __restrict__ w3b,
    unsigned short* __restrict__ h,
    const int* __restrict__ counts, const int* __restrict__ offs,
    const int* __restrict__ toks) {
    const int e = blockIdx.z;
    const int M = counts[e];
    const int m0 = blockIdx.x * 128;
    if (m0 >= M) return;
    const int n0 = blockIdx.y * 128;

    __shared__ unsigned short As[128 * 64];
    __shared__ unsigned short B1s[128 * 64];
    __shared__ unsigned short B3s[128 * 64];

    const int t = threadIdx.x;
    const int rb = t >> 3;                          // staged row within 32-row group
    const int kc = ((t & 7) ^ (rb & 7)) * 8;        // swizzled k-chunk to fetch
    const int* tl = toks + e * CAP;
    int arow[4], brow[4];
#pragma unroll
    for (int i = 0; i < 4; ++i) {
        arow[i] = tl[min(m0 + rb + i * 32, M - 1)];
        brow[i] = min(n0 + rb + i * 32, HID - 1);
    }
    const unsigned short* w1e = w1b + (size_t)e * HID * DIM;
    const unsigned short* w3e = w3b + (size_t)e * HID * DIM;

    floatx4 acc1[4][4], acc3[4][4];
#pragma unroll
    for (int a = 0; a < 4; ++a)
#pragma unroll
        for (int b = 0; b < 4; ++b) {
            acc1[a][b] = (floatx4){0.f, 0.f, 0.f, 0.f};
            acc3[a][b] = (floatx4){0.f, 0.f, 0.f, 0.f};
        }

    const int wv = t >> 6, lane = t & 63;
    const int wm = (wv & 1) * 64, wn = (wv >> 1) * 64;
    const int lr = lane & 15, lq = lane >> 4;
    const int sw = lane & 7;

    for (int k0 = 0; k0 < DIM; k0 += 64) {
#pragma unroll
        for (int i = 0; i < 4; ++i) {
            const int ldso = (i * 256 + t) * 8;
            gl2lds16(xb + (size_t)arow[i] * DIM + k0 + kc, &As[ldso]);
            gl2lds16(w1e + (size_t)brow[i] * DIM + k0 + kc, &B1s[ldso]);
            gl2lds16(w3e + (size_t)brow[i] * DIM + k0 + kc, &B3s[ldso]);
        }
        __syncthreads();
#pragma unroll
        for (int kk = 0; kk < 64; kk += 32) {
            const int pc = (((kk >> 3) + lq) ^ sw) * 8;   // physical chunk offset
            bf16x8 af[4];
#pragma unroll
            for (int mi = 0; mi < 4; ++mi)
                af[mi] = *(const bf16x8*)&As[(wm + mi * 16 + lr) * 64 + pc];
#pragma unroll
            for (int ni = 0; ni < 4; ++ni) {
                bf16x8 b1 = *(const bf16x8*)&B1s[(wn + ni * 16 + lr) * 64 + pc];
                bf16x8 b3 = *(const bf16x8*)&B3s[(wn + ni * 16 + lr) * 64 + pc];
#pragma unroll
                for (int mi = 0; mi < 4; ++mi) {
                    acc1[mi][ni] = __builtin_amdgcn_mfma_f32_16x16x32_bf16(af[mi], b1, acc1[mi][ni], 0, 0, 0);
                    acc3[mi][ni] = __builtin_amdgcn_mfma_f32_16x16x32_bf16(af[mi], b3, acc3[mi][ni], 0, 0, 0);
                }
            }
        }
        __syncthreads();
    }

    const int hb = offs[e];
#pragma unroll
    for (int mi = 0; mi < 4; ++mi) {
#pragma unroll
        for (int rg = 0; rg < 4; ++rg) {
            const int gm = m0 + wm + mi * 16 + lq * 4 + rg;
            if (gm >= M) continue;
            unsigned short* hrow = h + (size_t)(hb + gm) * HPAD;
#pragma unroll
            for (int ni = 0; ni < 4; ++ni) {
                const int col = n0 + wn + ni * 16 + lr;
                if (col >= HPAD) continue;
                float z1 = acc1[mi][ni][rg];
                float z3 = acc3[mi][ni][rg];
                float hv = z1 / (1.f + __expf(-z1)) * z3;   // silu(z1)*z3
                hrow[col] = f2bf(hv);
            }
        }
    }
}

// ---------------- stage-2: split-K=2, bf16 partials y[kh][slot] = h[slot,khalf] @ w2^T ----
// z = e*2 + kh. 2048 active-capable blocks (vs 1024) -> less dispatch-round tail.
__global__ __launch_bounds__(256, 2) void gemm2_kernel(
    const unsigned short* __restrict__ h,
    const unsigned short* __restrict__ w2b,
    unsigned short* __restrict__ yh,            // [2][NSLOT][DIM] bf16 partials
    const int* __restrict__ counts, const int* __restrict__ offs) {
    const int e  = blockIdx.z >> 1;
    const int kh = blockIdx.z & 1;
    const int M = counts[e];
    const int m0 = blockIdx.x * 128;
    if (m0 >= M) return;
    const int n0 = blockIdx.y * 128;

    __shared__ unsigned short As[128 * 64];
    __shared__ unsigned short Bs[128 * 64];

    const int t = threadIdx.x;
    const int rb = t >> 3;
    const int kc = ((t & 7) ^ (rb & 7)) * 8;        // swizzled k-chunk
    const int hb = offs[e];
    int arow[4], brow[4];
#pragma unroll
    for (int i = 0; i < 4; ++i) {
        arow[i] = hb + min(m0 + rb + i * 32, M - 1);
        brow[i] = n0 + rb + i * 32;                 // always < 1024
    }
    const unsigned short* w2e = w2b + (size_t)e * DIM * HPAD;

    floatx4 acc[4][4];
#pragma unroll
    for (int a = 0; a < 4; ++a)
#pragma unroll
        for (int b = 0; b < 4; ++b) acc[a][b] = (floatx4){0.f, 0.f, 0.f, 0.f};

    const int wv = t >> 6, lane = t & 63;
    const int wm = (wv & 1) * 64, wn = (wv >> 1) * 64;
    const int lr = lane & 15, lq = lane >> 4;
    const int sw = lane & 7;

    // K split: kh=0 -> iters [0,22), kh=1 -> iters [22,43)
    const int kbeg = kh ? 22 * 64 : 0;
    const int kend = kh ? HPAD : 22 * 64;
    for (int k0 = kbeg; k0 < kend; k0 += 64) {
#pragma unroll
        for (int i = 0; i < 4; ++i) {
            const int ldso = (i * 256 + t) * 8;
            gl2lds16(h + (size_t)arow[i] * HPAD + k0 + kc, &As[ldso]);
            gl2lds16(w2e + (size_t)brow[i] * HPAD + k0 + kc, &Bs[ldso]);
        }
        __syncthreads();
#pragma unroll
        for (int kk = 0; kk < 64; kk += 32) {
            const int pc = (((kk >> 3) + lq) ^ sw) * 8;
            bf16x8 af[4];
#pragma unroll
            for (int mi = 0; mi < 4; ++mi)
                af[mi] = *(const bf16x8*)&As[(wm + mi * 16 + lr) * 64 + pc];
#pragma unroll
            for (int ni = 0; ni < 4; ++ni) {
                bf16x8 bf = *(const bf16x8*)&Bs[(wn + ni * 16 + lr) * 64 + pc];
#pragma unroll
                for (int mi = 0; mi < 4; ++mi)
                    acc[mi][ni] = __builtin_amdgcn_mfma_f32_16x16x32_bf16(af[mi], bf, acc[mi][ni], 0, 0, 0);
            }
        }
        __syncthreads();
    }

    unsigned short* ybase = yh + (size_t)kh * NSLOT * DIM;
#pragma unroll
    for (int mi = 0; mi < 4; ++mi) {
#pragma unroll
        for (int rg = 0; rg < 4; ++rg) {
            const int gm = m0 + wm + mi * 16 + lq * 4 + rg;
            if (gm >= M) continue;
            unsigned short* yrow = ybase + (size_t)(hb + gm) * DIM;
#pragma unroll
            for (int ni = 0; ni < 4; ++ni) {
                const int col = n0 + wn + ni * 16 + lr;
                yrow[col] = f2bf(acc[mi][ni][rg]);
            }
        }
    }
}

// ---------------- combine: out[tok] = w0*(y0[s0]+y1[s0]) + w1*(y0[s1]+y1[s1]) ----------------
__global__ void combine_kernel(const unsigned short* __restrict__ yh,
                               const int* __restrict__ meta,
                               const float* __restrict__ tokw,
                               const int* __restrict__ offs,
                               float* __restrict__ out) {
    const int tok = blockIdx.x;
    const int t = threadIdx.x;                      // 256 threads x 4 floats = 1024
    const int m0 = meta[tok * 2], m1 = meta[tok * 2 + 1];
    const float w0 = tokw[tok * 2], w1 = tokw[tok * 2 + 1];
    const size_t r0 = (size_t)(offs[m0 >> 16] + (m0 & 0xffff)) * DIM;
    const size_t r1 = (size_t)(offs[m1 >> 16] + (m1 & 0xffff)) * DIM;
    const unsigned short* p0 = yh;
    const unsigned short* p1 = yh + (size_t)NSLOT * DIM;
    uint2 a0 = ((const uint2*)(p0 + r0))[t];
    uint2 a1 = ((const uint2*)(p1 + r0))[t];
    uint2 b0 = ((const uint2*)(p0 + r1))[t];
    uint2 b1 = ((const uint2*)(p1 + r1))[t];
    float4 o;
    o.x = w0 * (bf2f(a0.x & 0xffff) + bf2f(a1.x & 0xffff)) + w1 * (bf2f(b0.x & 0xffff) + bf2f(b1.x & 0xffff));
    o.y = w0 * (bf2f(a0.x >> 16)    + bf2f(a1.x >> 16))    + w1 * (bf2f(b0.x >> 16)    + bf2f(b1.x >> 16));
    o.z = w0 * (bf2f(a0.y & 0xffff) + bf2f(a1.y & 0xffff)) + w1 * (bf2f(b0.y & 0xffff) + bf2f(b1.y & 0xffff));
    o.w = w0 * (bf2f(a0.y >> 16)    + bf2f(a1.y >> 16))    + w1 * (bf2f(b0.y >> 16)    + bf2f(b1.y >> 16));
    ((float4*)(out + (size_t)tok * DIM))[t] = o;
}

extern "C" void kernel_launch(void* const* d_in, const int* in_sizes, int n_in,
                              void* d_out, int out_size, void* d_ws, size_t ws_size,
                              hipStream_t stream) {
    const float* x  = (const float*)d_in[0];
    const float* gw = (const float*)d_in[1];
    const float* w1 = (const float*)d_in[2];
    const float* w2 = (const float*)d_in[3];   // dict order: w1, w2, w3
    const float* w3 = (const float*)d_in[4];
    float* out = (float*)d_out;

    char* ws = (char*)d_ws;
    size_t o = 0;
    auto alloc = [&](size_t bytes) -> void* {
        void* p = ws + o;
        o += (bytes + 255) & ~(size_t)255;
        return p;
    };
    unsigned short* xb   = (unsigned short*)alloc((size_t)NTOK * DIM * 2);       // 16.8 MB
    unsigned short* w1b  = (unsigned short*)alloc((size_t)NE * HID * DIM * 2);   // 44.7 MB
    unsigned short* w3b  = (unsigned short*)alloc((size_t)NE * HID * DIM * 2);   // 44.7 MB
    unsigned short* w2b  = (unsigned short*)alloc((size_t)NE * DIM * HPAD * 2);  // 45.1 MB
    unsigned short* hbuf = (unsigned short*)alloc((size_t)NSLOT * HPAD * 2);     // 90.2 MB
    int*   toks   = (int*)alloc((size_t)NE * CAP * 4);
    int*   meta   = (int*)alloc((size_t)NTOK * 2 * 4);
    float* tokw   = (float*)alloc((size_t)NTOK * 2 * 4);
    int*   counts = (int*)alloc(256);
    float* psum   = (float*)alloc(256);
    int*   offs   = (int*)alloc(256);
    if (o > ws_size) return;
    // bf16 split-K partials: 2 x 16384 x 1024 x 2 B = 67.1 MB, aliased over
    // xb+w1b+w3b (106.2 MB) -- all three are dead once gemm1 completes, and
    // gemm2 (which writes yh) is stream-ordered after gemm1.
    unsigned short* yh = (unsigned short*)xb;

    hipMemsetAsync(counts, 0, 256, stream);
    hipMemsetAsync(psum, 0, 256, stream);

    router_kernel<<<2048, 256, 0, stream>>>(x, gw, xb, toks, meta, tokw, counts, psum);
    finalize_kernel<<<1, 64, 0, stream>>>(counts, offs, psum, out + (size_t)NTOK * DIM);
    convert_w_kernel<<<65696, 256, 0, stream>>>(w1, w3, w2, w1b, w3b, w2b);
    gemm1_kernel<<<dim3(64, 22, 8), 256, 0, stream>>>(xb, w1b, w3b, hbuf, counts, offs, toks);
    gemm2_kernel<<<dim3(64, 8, 16), 256, 0, stream>>>(hbuf, w2b, yh, counts, offs);
    combine_kernel<<<NTOK, 256, 0, stream>>>(yh, meta, tokw, offs, out);
}

// Round 4
// 863.935 us; speedup vs baseline: 1.2225x; 1.2225x over previous
//
#include <hip/hip_runtime.h>
#include <hip/hip_bf16.h>
#include <stdint.h>

#define DIM   1024
#define NE    8
#define HID   2730
#define HPAD  2752      // stage-2 K padded to multiple of 64 (43 k-iters)
#define NTOK  8192      // B*N = 4*2048
#define CAP   8192      // max tokens per expert
#define NSLOT 16384     // NTOK * TOP_K
#define MAXBLK 136      // sum_e ceil(M_e/128) <= 8192*2/128 + 8 = 136

typedef __bf16 bf16x8 __attribute__((ext_vector_type(8)));
typedef float  floatx4 __attribute__((ext_vector_type(4)));

__device__ __forceinline__ unsigned short f2bf(float f) {
    union { float f; unsigned int u; } v; v.f = f;
    unsigned int u = v.u;
    unsigned int r = (u + 0x7fffu + ((u >> 16) & 1u)) >> 16;  // RNE
    return (unsigned short)r;
}

__device__ __forceinline__ float bf2f(unsigned short b) {
    union { unsigned int u; float f; } v; v.u = (unsigned int)b << 16;
    return v.f;
}

__device__ __forceinline__ void gl2lds16(const void* g, void* l) {
    __builtin_amdgcn_global_load_lds((const __attribute__((address_space(1))) void*)g,
                                     (__attribute__((address_space(3))) void*)l,
                                     16, 0, 0);
}

// ---------------- merged weight conversion (w1, w3, w2) + scalar init ----------------
__global__ void convert_w_kernel(const float* __restrict__ w1, const float* __restrict__ w3,
                                 const float* __restrict__ w2,
                                 unsigned short* __restrict__ w1b, unsigned short* __restrict__ w3b,
                                 unsigned short* __restrict__ w2b,
                                 int* __restrict__ counts, float* __restrict__ psum) {
    const int HALF = (NE * HID * DIM) / 4;   // 5,591,040 float4 chunks per w1/w3
    const int W13  = 2 * HALF;               // 11,182,080
    int gid = blockIdx.x * 256 + threadIdx.x;
    if (blockIdx.x == 0 && threadIdx.x < 64) {   // runs before router (stream order)
        counts[threadIdx.x & 15] = 0;
        psum[threadIdx.x & 15] = 0.f;
    }
    if (gid < W13) {
        const float* src; unsigned short* dst; int j;
        if (gid < HALF) { src = w1; dst = w1b; j = gid; }
        else            { src = w3; dst = w3b; j = gid - HALF; }
        float4 v = ((const float4*)src)[j];
        uint2 o;
        o.x = (unsigned)f2bf(v.x) | ((unsigned)f2bf(v.y) << 16);
        o.y = (unsigned)f2bf(v.z) | ((unsigned)f2bf(v.w) << 16);
        *(uint2*)(dst + (size_t)j * 4) = o;
    } else {
        int i = gid - W13;                   // 8192 rows * 688 chunks
        int r = i / 688;
        int c = (i - r * 688) * 4;
        const float* src = w2 + r * HID;
        unsigned short q[4];
#pragma unroll
        for (int j = 0; j < 4; ++j) {
            int col = c + j;
            q[j] = (col < HID) ? f2bf(src[col]) : (unsigned short)0;  // zero pad annihilates h pad cols
        }
        uint2 o;
        o.x = (unsigned)q[0] | ((unsigned)q[1] << 16);
        o.y = (unsigned)q[2] | ((unsigned)q[3] << 16);
        *(uint2*)(w2b + (size_t)r * HPAD + c) = o;
    }
}

// ---------------- router (also emits xb = bf16(x)) ----------------
__global__ void router_kernel(const float* __restrict__ x, const float* __restrict__ gw,
                              unsigned short* __restrict__ xb,
                              int* __restrict__ toks, int* __restrict__ meta,
                              float* __restrict__ tokw,
                              int* __restrict__ counts, float* __restrict__ psum) {
    __shared__ float gws[NE * DIM];        // 32 KB
    __shared__ float pblk[4][NE];
    int t = threadIdx.x;
    for (int i = t; i < NE * DIM; i += 256) gws[i] = gw[i];
    __syncthreads();

    int wv = t >> 6, lane = t & 63;
    int tok = blockIdx.x * 4 + wv;
    const float4* x4 = (const float4*)(x + (size_t)tok * DIM);
    uint2* xbrow = (uint2*)(xb + (size_t)tok * DIM);

    float p[NE];
#pragma unroll
    for (int e = 0; e < NE; ++e) p[e] = 0.f;
#pragma unroll
    for (int c = 0; c < 4; ++c) {
        float4 xv = x4[c * 64 + lane];
        uint2 o;
        o.x = (unsigned)f2bf(xv.x) | ((unsigned)f2bf(xv.y) << 16);
        o.y = (unsigned)f2bf(xv.z) | ((unsigned)f2bf(xv.w) << 16);
        xbrow[c * 64 + lane] = o;
#pragma unroll
        for (int e = 0; e < NE; ++e) {
            float4 gv = ((const float4*)(gws + e * DIM))[c * 64 + lane];
            p[e] += xv.x * gv.x + xv.y * gv.y + xv.z * gv.z + xv.w * gv.w;
        }
    }
#pragma unroll
    for (int e = 0; e < NE; ++e)
#pragma unroll
        for (int s = 32; s; s >>= 1) p[e] += __shfl_xor(p[e], s, 64);

    if (lane == 0) {
        float mx = p[0];
#pragma unroll
        for (int e = 1; e < NE; ++e) mx = fmaxf(mx, p[e]);
        float ex[NE], s = 0.f;
#pragma unroll
        for (int e = 0; e < NE; ++e) { ex[e] = __expf(p[e] - mx); s += ex[e]; }
        float inv = 1.f / s;
        int i1 = 0, i2 = 0; float v1 = -1.f, v2 = -1.f;
#pragma unroll
        for (int e = 0; e < NE; ++e) {
            float pe = ex[e] * inv;
            pblk[wv][e] = pe;
            if (pe > v1)      { v2 = v1; i2 = i1; v1 = pe; i1 = e; }
            else if (pe > v2) { v2 = pe; i2 = e; }
        }
        float wn = 1.f / (v1 + v2);
        int p1 = atomicAdd(&counts[i1], 1);
        toks[i1 * CAP + p1] = tok;
        meta[tok * 2]     = (i1 << 16) | p1;
        tokw[tok * 2]     = v1 * wn;
        int p2 = atomicAdd(&counts[i2], 1);
        toks[i2 * CAP + p2] = tok;
        meta[tok * 2 + 1] = (i2 << 16) | p2;
        tokw[tok * 2 + 1] = v2 * wn;
    }
    __syncthreads();
    if (t < NE) {
        float s = pblk[0][t] + pblk[1][t] + pblk[2][t] + pblk[3][t];
        atomicAdd(&psum[t], s);
    }
}

// finalize: prefix offsets, aux loss, and the live m-block table
// (linear m-slot -> (expert, m0); unused slots get m0=INT_MAX so blocks exit).
__global__ void finalize_kernel(const int* __restrict__ counts, int* __restrict__ offs,
                                const float* __restrict__ psum, float* __restrict__ aux_out,
                                int* __restrict__ blk_e, int* __restrict__ blk_m0) {
    if (threadIdx.x == 0) {
        int off = 0, nb = 0;
        for (int e = 0; e < NE; ++e) {
            offs[e] = off;
            int M = counts[e];
            off += M;
            for (int m0 = 0; m0 < M; m0 += 128) { blk_e[nb] = e; blk_m0[nb] = m0; ++nb; }
        }
        for (; nb < MAXBLK; ++nb) { blk_e[nb] = 0; blk_m0[nb] = 0x7fffffff; }
        float s = 0.f;
        for (int e = 0; e < NE; ++e) {
            float d = psum[e] * (1.f / NTOK) - (1.f / NE);
            s += d * d;
        }
        aux_out[0] = 0.01f * s * (1.f / NE);
    }
}

// ---------------- stage-1: h = silu(x@w1^T) * (x@w3^T), gathered rows ----------------
// Grid: x = n-blocks (innermost, 22) so consecutive blocks share the A m-tile and
// stream the weight tiles (round-2 verified-good order); y = live m-slot table.
// LDS XOR swizzle on 16B chunks kills bank conflicts (verified: 5.35e7 -> 0).
__global__ __launch_bounds__(256, 2) void gemm1_kernel(
    const unsigned short* __restrict__ xb,
    const unsigned short* __restrict__ w1b,
    const unsigned short* __restrict__ w3b,
    unsigned short* __restrict__ h,
    const int* __restrict__ counts, const int* __restrict__ offs,
    const int* __restrict__ toks,
    const int* __restrict__ blk_e, const int* __restrict__ blk_m0) {
    const int e  = blk_e[blockIdx.y];
    const int m0 = blk_m0[blockIdx.y];
    const int M  = counts[e];
    if (m0 >= M) return;
    const int n0 = blockIdx.x * 128;

    __shared__ unsigned short As[128 * 64];
    __shared__ unsigned short B1s[128 * 64];
    __shared__ unsigned short B3s[128 * 64];

    const int t = threadIdx.x;
    const int rb = t >> 3;                          // staged row within 32-row group
    const int kc = ((t & 7) ^ (rb & 7)) * 8;        // swizzled k-chunk to fetch
    const int* tl = toks + e * CAP;
    int arow[4], brow[4];
#pragma unroll
    for (int i = 0; i < 4; ++i) {
        arow[i] = tl[min(m0 + rb + i * 32, M - 1)];
        brow[i] = min(n0 + rb + i * 32, HID - 1);
    }
    const unsigned short* w1e = w1b + (size_t)e * HID * DIM;
    const unsigned short* w3e = w3b + (size_t)e * HID * DIM;

    floatx4 acc1[4][4], acc3[4][4];
#pragma unroll
    for (int a = 0; a < 4; ++a)
#pragma unroll
        for (int b = 0; b < 4; ++b) {
            acc1[a][b] = (floatx4){0.f, 0.f, 0.f, 0.f};
            acc3[a][b] = (floatx4){0.f, 0.f, 0.f, 0.f};
        }

    const int wv = t >> 6, lane = t & 63;
    const int wm = (wv & 1) * 64, wn = (wv >> 1) * 64;
    const int lr = lane & 15, lq = lane >> 4;
    const int sw = lane & 7;

    for (int k0 = 0; k0 < DIM; k0 += 64) {
#pragma unroll
        for (int i = 0; i < 4; ++i) {
            const int ldso = (i * 256 + t) * 8;
            gl2lds16(xb + (size_t)arow[i] * DIM + k0 + kc, &As[ldso]);
            gl2lds16(w1e + (size_t)brow[i] * DIM + k0 + kc, &B1s[ldso]);
            gl2lds16(w3e + (size_t)brow[i] * DIM + k0 + kc, &B3s[ldso]);
        }
        __syncthreads();
#pragma unroll
        for (int kk = 0; kk < 64; kk += 32) {
            const int pc = (((kk >> 3) + lq) ^ sw) * 8;   // physical chunk offset
            bf16x8 af[4];
#pragma unroll
            for (int mi = 0; mi < 4; ++mi)
                af[mi] = *(const bf16x8*)&As[(wm + mi * 16 + lr) * 64 + pc];
#pragma unroll
            for (int ni = 0; ni < 4; ++ni) {
                bf16x8 b1 = *(const bf16x8*)&B1s[(wn + ni * 16 + lr) * 64 + pc];
                bf16x8 b3 = *(const bf16x8*)&B3s[(wn + ni * 16 + lr) * 64 + pc];
#pragma unroll
                for (int mi = 0; mi < 4; ++mi) {
                    acc1[mi][ni] = __builtin_amdgcn_mfma_f32_16x16x32_bf16(af[mi], b1, acc1[mi][ni], 0, 0, 0);
                    acc3[mi][ni] = __builtin_amdgcn_mfma_f32_16x16x32_bf16(af[mi], b3, acc3[mi][ni], 0, 0, 0);
                }
            }
        }
        __syncthreads();
    }

    const int hb = offs[e];
#pragma unroll
    for (int mi = 0; mi < 4; ++mi) {
#pragma unroll
        for (int rg = 0; rg < 4; ++rg) {
            const int gm = m0 + wm + mi * 16 + lq * 4 + rg;
            if (gm >= M) continue;
            unsigned short* hrow = h + (size_t)(hb + gm) * HPAD;
#pragma unroll
            for (int ni = 0; ni < 4; ++ni) {
                const int col = n0 + wn + ni * 16 + lr;
                if (col >= HPAD) continue;
                float z1 = acc1[mi][ni][rg];
                float z3 = acc3[mi][ni][rg];
                float hv = z1 / (1.f + __expf(-z1)) * z3;   // silu(z1)*z3
                hrow[col] = f2bf(hv);
            }
        }
    }
}

// ---------------- stage-2: split-K=2, bf16 partials y[kh][slot] = h[slot,khalf] @ w2^T ----
// x = n (8, innermost), y = live m-slot table, z = K-half. ~2048 live blocks.
__global__ __launch_bounds__(256, 2) void gemm2_kernel(
    const unsigned short* __restrict__ h,
    const unsigned short* __restrict__ w2b,
    unsigned short* __restrict__ yh,            // [2][NSLOT][DIM] bf16 partials
    const int* __restrict__ counts, const int* __restrict__ offs,
    const int* __restrict__ blk_e, const int* __restrict__ blk_m0) {
    const int e  = blk_e[blockIdx.y];
    const int m0 = blk_m0[blockIdx.y];
    const int M  = counts[e];
    if (m0 >= M) return;
    const int kh = blockIdx.z;
    const int n0 = blockIdx.x * 128;

    __shared__ unsigned short As[128 * 64];
    __shared__ unsigned short Bs[128 * 64];

    const int t = threadIdx.x;
    const int rb = t >> 3;
    const int kc = ((t & 7) ^ (rb & 7)) * 8;        // swizzled k-chunk
    const int hb = offs[e];
    int arow[4], brow[4];
#pragma unroll
    for (int i = 0; i < 4; ++i) {
        arow[i] = hb + min(m0 + rb + i * 32, M - 1);
        brow[i] = n0 + rb + i * 32;                 // always < 1024
    }
    const unsigned short* w2e = w2b + (size_t)e * DIM * HPAD;

    floatx4 acc[4][4];
#pragma unroll
    for (int a = 0; a < 4; ++a)
#pragma unroll
        for (int b = 0; b < 4; ++b) acc[a][b] = (floatx4){0.f, 0.f, 0.f, 0.f};

    const int wv = t >> 6, lane = t & 63;
    const int wm = (wv & 1) * 64, wn = (wv >> 1) * 64;
    const int lr = lane & 15, lq = lane >> 4;
    const int sw = lane & 7;

    // K split: kh=0 -> iters [0,22), kh=1 -> iters [22,43)
    const int kbeg = kh ? 22 * 64 : 0;
    const int kend = kh ? HPAD : 22 * 64;
    for (int k0 = kbeg; k0 < kend; k0 += 64) {
#pragma unroll
        for (int i = 0; i < 4; ++i) {
            const int ldso = (i * 256 + t) * 8;
            gl2lds16(h + (size_t)arow[i] * HPAD + k0 + kc, &As[ldso]);
            gl2lds16(w2e + (size_t)brow[i] * HPAD + k0 + kc, &Bs[ldso]);
        }
        __syncthreads();
#pragma unroll
        for (int kk = 0; kk < 64; kk += 32) {
            const int pc = (((kk >> 3) + lq) ^ sw) * 8;
            bf16x8 af[4];
#pragma unroll
            for (int mi = 0; mi < 4; ++mi)
                af[mi] = *(const bf16x8*)&As[(wm + mi * 16 + lr) * 64 + pc];
#pragma unroll
            for (int ni = 0; ni < 4; ++ni) {
                bf16x8 bf = *(const bf16x8*)&Bs[(wn + ni * 16 + lr) * 64 + pc];
#pragma unroll
                for (int mi = 0; mi < 4; ++mi)
                    acc[mi][ni] = __builtin_amdgcn_mfma_f32_16x16x32_bf16(af[mi], bf, acc[mi][ni], 0, 0, 0);
            }
        }
        __syncthreads();
    }

    unsigned short* ybase = yh + (size_t)kh * NSLOT * DIM;
#pragma unroll
    for (int mi = 0; mi < 4; ++mi) {
#pragma unroll
        for (int rg = 0; rg < 4; ++rg) {
            const int gm = m0 + wm + mi * 16 + lq * 4 + rg;
            if (gm >= M) continue;
            unsigned short* yrow = ybase + (size_t)(hb + gm) * DIM;
#pragma unroll
            for (int ni = 0; ni < 4; ++ni) {
                const int col = n0 + wn + ni * 16 + lr;
                yrow[col] = f2bf(acc[mi][ni][rg]);
            }
        }
    }
}

// ---------------- combine: out[tok] = w0*(y0[s0]+y1[s0]) + w1*(y0[s1]+y1[s1]) ----------------
__global__ void combine_kernel(const unsigned short* __restrict__ yh,
                               const int* __restrict__ meta,
                               const float* __restrict__ tokw,
                               const int* __restrict__ offs,
                               float* __restrict__ out) {
    const int tok = blockIdx.x;
    const int t = threadIdx.x;                      // 256 threads x 4 floats = 1024
    const int m0 = meta[tok * 2], m1 = meta[tok * 2 + 1];
    const float w0 = tokw[tok * 2], w1 = tokw[tok * 2 + 1];
    const size_t r0 = (size_t)(offs[m0 >> 16] + (m0 & 0xffff)) * DIM;
    const size_t r1 = (size_t)(offs[m1 >> 16] + (m1 & 0xffff)) * DIM;
    const unsigned short* p0 = yh;
    const unsigned short* p1 = yh + (size_t)NSLOT * DIM;
    uint2 a0 = ((const uint2*)(p0 + r0))[t];
    uint2 a1 = ((const uint2*)(p1 + r0))[t];
    uint2 b0 = ((const uint2*)(p0 + r1))[t];
    uint2 b1 = ((const uint2*)(p1 + r1))[t];
    float4 o;
    o.x = w0 * (bf2f(a0.x & 0xffff) + bf2f(a1.x & 0xffff)) + w1 * (bf2f(b0.x & 0xffff) + bf2f(b1.x & 0xffff));
    o.y = w0 * (bf2f(a0.x >> 16)    + bf2f(a1.x >> 16))    + w1 * (bf2f(b0.x >> 16)    + bf2f(b1.x >> 16));
    o.z = w0 * (bf2f(a0.y & 0xffff) + bf2f(a1.y & 0xffff)) + w1 * (bf2f(b0.y & 0xffff) + bf2f(b1.y & 0xffff));
    o.w = w0 * (bf2f(a0.y >> 16)    + bf2f(a1.y >> 16))    + w1 * (bf2f(b0.y >> 16)    + bf2f(b1.y >> 16));
    ((float4*)(out + (size_t)tok * DIM))[t] = o;
}

extern "C" void kernel_launch(void* const* d_in, const int* in_sizes, int n_in,
                              void* d_out, int out_size, void* d_ws, size_t ws_size,
                              hipStream_t stream) {
    const float* x  = (const float*)d_in[0];
    const float* gw = (const float*)d_in[1];
    const float* w1 = (const float*)d_in[2];
    const float* w2 = (const float*)d_in[3];   // dict order: w1, w2, w3
    const float* w3 = (const float*)d_in[4];
    float* out = (float*)d_out;

    char* ws = (char*)d_ws;
    size_t o = 0;
    auto alloc = [&](size_t bytes) -> void* {
        void* p = ws + o;
        o += (bytes + 255) & ~(size_t)255;
        return p;
    };
    unsigned short* xb   = (unsigned short*)alloc((size_t)NTOK * DIM * 2);       // 16.8 MB
    unsigned short* w1b  = (unsigned short*)alloc((size_t)NE * HID * DIM * 2);   // 44.7 MB
    unsigned short* w3b  = (unsigned short*)alloc((size_t)NE * HID * DIM * 2);   // 44.7 MB
    unsigned short* w2b  = (unsigned short*)alloc((size_t)NE * DIM * HPAD * 2);  // 45.1 MB
    unsigned short* hbuf = (unsigned short*)alloc((size_t)NSLOT * HPAD * 2);     // 90.2 MB
    int*   toks   = (int*)alloc((size_t)NE * CAP * 4);
    int*   meta   = (int*)alloc((size_t)NTOK * 2 * 4);
    float* tokw   = (float*)alloc((size_t)NTOK * 2 * 4);
    int*   counts = (int*)alloc(256);
    float* psum   = (float*)alloc(256);
    int*   offs   = (int*)alloc(256);
    int*   blk_e  = (int*)alloc(MAXBLK * 4);
    int*   blk_m0 = (int*)alloc(MAXBLK * 4);
    if (o > ws_size) return;
    // bf16 split-K partials: 2 x 16384 x 1024 x 2 B = 67.1 MB, aliased over
    // xb+w1b+w3b (106.2 MB) -- all three are dead once gemm1 completes, and
    // gemm2 (which writes yh) is stream-ordered after gemm1.
    unsigned short* yh = (unsigned short*)xb;

    convert_w_kernel<<<65696, 256, 0, stream>>>(w1, w3, w2, w1b, w3b, w2b, counts, psum);
    router_kernel<<<2048, 256, 0, stream>>>(x, gw, xb, toks, meta, tokw, counts, psum);
    finalize_kernel<<<1, 64, 0, stream>>>(counts, offs, psum, out + (size_t)NTOK * DIM, blk_e, blk_m0);
    gemm1_kernel<<<dim3(22, MAXBLK, 1), 256, 0, stream>>>(xb, w1b, w3b, hbuf, counts, offs, toks, blk_e, blk_m0);
    gemm2_kernel<<<dim3(8, MAXBLK, 2), 256, 0, stream>>>(hbuf, w2b, yh, counts, offs, blk_e, blk_m0);
    combine_kernel<<<NTOK, 256, 0, stream>>>(yh, meta, tokw, offs, out);
}

// Round 5
// 796.400 us; speedup vs baseline: 1.3262x; 1.0848x over previous
//
#include <hip/hip_runtime.h>
#include <hip/hip_bf16.h>
#include <stdint.h>

#define DIM   1024
#define NE    8
#define HID   2730
#define HPAD  2752      // stage-2 K padded to multiple of 64 (43 k-iters)
#define NTOK  8192      // B*N = 4*2048
#define CAP   8192      // max tokens per expert
#define NSLOT 16384     // NTOK * TOP_K
#define MAXBLK 136      // sum_e ceil(M_e/128) <= 16384/128 + 8 = 136

typedef __bf16 bf16x8 __attribute__((ext_vector_type(8)));
typedef float  floatx4 __attribute__((ext_vector_type(4)));

__device__ __forceinline__ unsigned short f2bf(float f) {
    union { float f; unsigned int u; } v; v.f = f;
    unsigned int u = v.u;
    unsigned int r = (u + 0x7fffu + ((u >> 16) & 1u)) >> 16;  // RNE
    return (unsigned short)r;
}

__device__ __forceinline__ float bf2f(unsigned short b) {
    union { unsigned int u; float f; } v; v.u = (unsigned int)b << 16;
    return v.f;
}

__device__ __forceinline__ void gl2lds16(const void* g, void* l) {
    __builtin_amdgcn_global_load_lds((const __attribute__((address_space(1))) void*)g,
                                     (__attribute__((address_space(3))) void*)l,
                                     16, 0, 0);
}

// ---------------- merged weight conversion (w1, w3, w2) + scalar init ----------------
__global__ void convert_w_kernel(const float* __restrict__ w1, const float* __restrict__ w3,
                                 const float* __restrict__ w2,
                                 unsigned short* __restrict__ w1b, unsigned short* __restrict__ w3b,
                                 unsigned short* __restrict__ w2b,
                                 int* __restrict__ counts, float* __restrict__ psum) {
    const int HALF = (NE * HID * DIM) / 4;   // 5,591,040 float4 chunks per w1/w3
    const int W13  = 2 * HALF;               // 11,182,080
    int gid = blockIdx.x * 256 + threadIdx.x;
    if (blockIdx.x == 0 && threadIdx.x < 64) {   // ordered before router (separate dispatch)
        counts[threadIdx.x & 15] = 0;
        psum[threadIdx.x & 15] = 0.f;
    }
    if (gid < W13) {
        const float* src; unsigned short* dst; int j;
        if (gid < HALF) { src = w1; dst = w1b; j = gid; }
        else            { src = w3; dst = w3b; j = gid - HALF; }
        float4 v = ((const float4*)src)[j];
        uint2 o;
        o.x = (unsigned)f2bf(v.x) | ((unsigned)f2bf(v.y) << 16);
        o.y = (unsigned)f2bf(v.z) | ((unsigned)f2bf(v.w) << 16);
        *(uint2*)(dst + (size_t)j * 4) = o;
    } else {
        int i = gid - W13;                   // 8192 rows * 688 chunks
        int r = i / 688;
        int c = (i - r * 688) * 4;
        const float* src = w2 + (size_t)r * HID;
        unsigned short q[4];
        if (c + 3 < HID) {                   // rows are 8B-aligned (2730*4 % 8 == 0)
            float2 v0 = *(const float2*)(src + c);
            float2 v1 = *(const float2*)(src + c + 2);
            q[0] = f2bf(v0.x); q[1] = f2bf(v0.y); q[2] = f2bf(v1.x); q[3] = f2bf(v1.y);
        } else {
#pragma unroll
            for (int j = 0; j < 4; ++j) {
                int col = c + j;
                q[j] = (col < HID) ? f2bf(src[col]) : (unsigned short)0;  // zero pad
            }
        }
        uint2 o;
        o.x = (unsigned)q[0] | ((unsigned)q[1] << 16);
        o.y = (unsigned)q[2] | ((unsigned)q[3] << 16);
        *(uint2*)(w2b + (size_t)r * HPAD + c) = o;
    }
}

// ---------------- router (also emits xb = bf16(x)) ----------------
__global__ void router_kernel(const float* __restrict__ x, const float* __restrict__ gw,
                              unsigned short* __restrict__ xb,
                              int* __restrict__ toks, int* __restrict__ meta,
                              float* __restrict__ tokw,
                              int* __restrict__ counts, float* __restrict__ psum) {
    __shared__ float gws[NE * DIM];        // 32 KB
    __shared__ float pblk[4][NE];
    int t = threadIdx.x;
    for (int i = t; i < NE * DIM; i += 256) gws[i] = gw[i];
    __syncthreads();

    int wv = t >> 6, lane = t & 63;
    int tok = blockIdx.x * 4 + wv;
    const float4* x4 = (const float4*)(x + (size_t)tok * DIM);
    uint2* xbrow = (uint2*)(xb + (size_t)tok * DIM);

    float p[NE];
#pragma unroll
    for (int e = 0; e < NE; ++e) p[e] = 0.f;
#pragma unroll
    for (int c = 0; c < 4; ++c) {
        float4 xv = x4[c * 64 + lane];
        uint2 o;
        o.x = (unsigned)f2bf(xv.x) | ((unsigned)f2bf(xv.y) << 16);
        o.y = (unsigned)f2bf(xv.z) | ((unsigned)f2bf(xv.w) << 16);
        xbrow[c * 64 + lane] = o;
#pragma unroll
        for (int e = 0; e < NE; ++e) {
            float4 gv = ((const float4*)(gws + e * DIM))[c * 64 + lane];
            p[e] += xv.x * gv.x + xv.y * gv.y + xv.z * gv.z + xv.w * gv.w;
        }
    }
#pragma unroll
    for (int e = 0; e < NE; ++e)
#pragma unroll
        for (int s = 32; s; s >>= 1) p[e] += __shfl_xor(p[e], s, 64);

    if (lane == 0) {
        float mx = p[0];
#pragma unroll
        for (int e = 1; e < NE; ++e) mx = fmaxf(mx, p[e]);
        float ex[NE], s = 0.f;
#pragma unroll
        for (int e = 0; e < NE; ++e) { ex[e] = __expf(p[e] - mx); s += ex[e]; }
        float inv = 1.f / s;
        int i1 = 0, i2 = 0; float v1 = -1.f, v2 = -1.f;
#pragma unroll
        for (int e = 0; e < NE; ++e) {
            float pe = ex[e] * inv;
            pblk[wv][e] = pe;
            if (pe > v1)      { v2 = v1; i2 = i1; v1 = pe; i1 = e; }
            else if (pe > v2) { v2 = pe; i2 = e; }
        }
        float wn = 1.f / (v1 + v2);
        int p1 = atomicAdd(&counts[i1], 1);
        toks[i1 * CAP + p1] = tok;
        meta[tok * 2]     = (i1 << 16) | p1;
        tokw[tok * 2]     = v1 * wn;
        int p2 = atomicAdd(&counts[i2], 1);
        toks[i2 * CAP + p2] = tok;
        meta[tok * 2 + 1] = (i2 << 16) | p2;
        tokw[tok * 2 + 1] = v2 * wn;
    }
    __syncthreads();
    if (t < NE) {
        float s = pblk[0][t] + pblk[1][t] + pblk[2][t] + pblk[3][t];
        atomicAdd(&psum[t], s);
    }
}

// finalize: prefix offsets, aux loss, and the live m-block table
__global__ void finalize_kernel(const int* __restrict__ counts, int* __restrict__ offs,
                                const float* __restrict__ psum, float* __restrict__ aux_out,
                                int* __restrict__ blk_e, int* __restrict__ blk_m0) {
    if (threadIdx.x == 0) {
        int off = 0, nb = 0;
        for (int e = 0; e < NE; ++e) {
            offs[e] = off;
            int M = counts[e];
            off += M;
            for (int m0 = 0; m0 < M; m0 += 128) { blk_e[nb] = e; blk_m0[nb] = m0; ++nb; }
        }
        for (; nb < MAXBLK; ++nb) { blk_e[nb] = 0; blk_m0[nb] = 0x7fffffff; }
        float s = 0.f;
        for (int e = 0; e < NE; ++e) {
            float d = psum[e] * (1.f / NTOK) - (1.f / NE);
            s += d * d;
        }
        aux_out[0] = 0.01f * s * (1.f / NE);
    }
}

// ---------------- stage-1: h = silu(x@w1^T) * (x@w3^T), gathered rows ----------------
// XCD swizzle: linear id (2992 = 8*22*17) -> q=id&7 (XCD class), x'=(id>>3)%22,
// r=(id>>3)/22, m-slot = q*17+r. All 22 n-blocks of one m-slot share id%8 -> same
// XCD -> A m-tile fetched once into that XCD's L2 (was ~8x duplicated, FETCH 525MB).
// Consecutive m-slots of one expert also stay on one XCD -> weight-tile L2 reuse.
// LDS XOR swizzle on 16B chunks kills bank conflicts (verified: 5.35e7 -> 0).
__global__ __launch_bounds__(256, 2) void gemm1_kernel(
    const unsigned short* __restrict__ xb,
    const unsigned short* __restrict__ w1b,
    const unsigned short* __restrict__ w3b,
    unsigned short* __restrict__ h,
    const int* __restrict__ counts, const int* __restrict__ offs,
    const int* __restrict__ toks,
    const int* __restrict__ blk_e, const int* __restrict__ blk_m0) {
    const int id  = blockIdx.y * 22 + blockIdx.x;
    const int q   = id & 7;
    const int rest = id >> 3;               // < 374
    const int xp  = rest % 22;
    const int rr  = rest / 22;              // < 17
    const int slot = q * 17 + rr;           // m-slot, < 136
    const int e  = blk_e[slot];
    const int m0 = blk_m0[slot];
    const int M  = counts[e];
    if (m0 >= M) return;
    const int n0 = xp * 128;

    __shared__ unsigned short As[128 * 64];
    __shared__ unsigned short B1s[128 * 64];
    __shared__ unsigned short B3s[128 * 64];

    const int t = threadIdx.x;
    const int rb = t >> 3;                          // staged row within 32-row group
    const int kc = ((t & 7) ^ (rb & 7)) * 8;        // swizzled k-chunk to fetch
    const int* tl = toks + e * CAP;
    int arow[4], brow[4];
#pragma unroll
    for (int i = 0; i < 4; ++i) {
        arow[i] = tl[min(m0 + rb + i * 32, M - 1)];
        brow[i] = min(n0 + rb + i * 32, HID - 1);
    }
    const unsigned short* w1e = w1b + (size_t)e * HID * DIM;
    const unsigned short* w3e = w3b + (size_t)e * HID * DIM;

    floatx4 acc1[4][4], acc3[4][4];
#pragma unroll
    for (int a = 0; a < 4; ++a)
#pragma unroll
        for (int b = 0; b < 4; ++b) {
            acc1[a][b] = (floatx4){0.f, 0.f, 0.f, 0.f};
            acc3[a][b] = (floatx4){0.f, 0.f, 0.f, 0.f};
        }

    const int wv = t >> 6, lane = t & 63;
    const int wm = (wv & 1) * 64, wn = (wv >> 1) * 64;
    const int lr = lane & 15, lq = lane >> 4;
    const int sw = lane & 7;

    for (int k0 = 0; k0 < DIM; k0 += 64) {
#pragma unroll
        for (int i = 0; i < 4; ++i) {
            const int ldso = (i * 256 + t) * 8;
            gl2lds16(xb + (size_t)arow[i] * DIM + k0 + kc, &As[ldso]);
            gl2lds16(w1e + (size_t)brow[i] * DIM + k0 + kc, &B1s[ldso]);
            gl2lds16(w3e + (size_t)brow[i] * DIM + k0 + kc, &B3s[ldso]);
        }
        __syncthreads();
#pragma unroll
        for (int kk = 0; kk < 64; kk += 32) {
            const int pc = (((kk >> 3) + lq) ^ sw) * 8;   // physical chunk offset
            bf16x8 af[4];
#pragma unroll
            for (int mi = 0; mi < 4; ++mi)
                af[mi] = *(const bf16x8*)&As[(wm + mi * 16 + lr) * 64 + pc];
#pragma unroll
            for (int ni = 0; ni < 4; ++ni) {
                bf16x8 b1 = *(const bf16x8*)&B1s[(wn + ni * 16 + lr) * 64 + pc];
                bf16x8 b3 = *(const bf16x8*)&B3s[(wn + ni * 16 + lr) * 64 + pc];
#pragma unroll
                for (int mi = 0; mi < 4; ++mi) {
                    acc1[mi][ni] = __builtin_amdgcn_mfma_f32_16x16x32_bf16(af[mi], b1, acc1[mi][ni], 0, 0, 0);
                    acc3[mi][ni] = __builtin_amdgcn_mfma_f32_16x16x32_bf16(af[mi], b3, acc3[mi][ni], 0, 0, 0);
                }
            }
        }
        __syncthreads();
    }

    const int hb = offs[e];
#pragma unroll
    for (int mi = 0; mi < 4; ++mi) {
#pragma unroll
        for (int rg = 0; rg < 4; ++rg) {
            const int gm = m0 + wm + mi * 16 + lq * 4 + rg;
            if (gm >= M) continue;
            unsigned short* hrow = h + (size_t)(hb + gm) * HPAD;
#pragma unroll
            for (int ni = 0; ni < 4; ++ni) {
                const int col = n0 + wn + ni * 16 + lr;
                if (col >= HPAD) continue;
                float z1 = acc1[mi][ni][rg];
                float z3 = acc3[mi][ni][rg];
                float hv = z1 / (1.f + __expf(-z1)) * z3;   // silu(z1)*z3
                hrow[col] = f2bf(hv);
            }
        }
    }
}

// ---------------- stage-2: split-K=2, bf16 partials y[kh][slot] = h[slot,khalf] @ w2^T ----
// XCD swizzle: 2176 = 8*8*34 blocks. q=id&7, x'=(id>>3)&7, g=(id>>3)>>3 (<34);
// group G=q*34+g -> (slot = G%136, kh = G/136). Same-(slot,kh) n-blocks share XCD.
__global__ __launch_bounds__(256, 2) void gemm2_kernel(
    const unsigned short* __restrict__ h,
    const unsigned short* __restrict__ w2b,
    unsigned short* __restrict__ yh,            // [2][NSLOT][DIM] bf16 partials
    const int* __restrict__ counts, const int* __restrict__ offs,
    const int* __restrict__ blk_e, const int* __restrict__ blk_m0) {
    const int id = (blockIdx.z * MAXBLK + blockIdx.y) * 8 + blockIdx.x;
    const int q  = id & 7;
    const int rest = id >> 3;               // < 272
    const int xp = rest & 7;
    const int g  = rest >> 3;               // < 34
    const int G  = q * 34 + g;              // < 272
    const int slot = G % MAXBLK;
    const int kh   = G / MAXBLK;
    const int e  = blk_e[slot];
    const int m0 = blk_m0[slot];
    const int M  = counts[e];
    if (m0 >= M) return;
    const int n0 = xp * 128;

    __shared__ unsigned short As[128 * 64];
    __shared__ unsigned short Bs[128 * 64];

    const int t = threadIdx.x;
    const int rb = t >> 3;
    const int kc = ((t & 7) ^ (rb & 7)) * 8;        // swizzled k-chunk
    const int hb = offs[e];
    int arow[4], brow[4];
#pragma unroll
    for (int i = 0; i < 4; ++i) {
        arow[i] = hb + min(m0 + rb + i * 32, M - 1);
        brow[i] = n0 + rb + i * 32;                 // always < 1024
    }
    const unsigned short* w2e = w2b + (size_t)e * DIM * HPAD;

    floatx4 acc[4][4];
#pragma unroll
    for (int a = 0; a < 4; ++a)
#pragma unroll
        for (int b = 0; b < 4; ++b) acc[a][b] = (floatx4){0.f, 0.f, 0.f, 0.f};

    const int wv = t >> 6, lane = t & 63;
    const int wm = (wv & 1) * 64, wn = (wv >> 1) * 64;
    const int lr = lane & 15, lq = lane >> 4;
    const int sw = lane & 7;

    // K split: kh=0 -> iters [0,22), kh=1 -> iters [22,43)
    const int kbeg = kh ? 22 * 64 : 0;
    const int kend = kh ? HPAD : 22 * 64;
    for (int k0 = kbeg; k0 < kend; k0 += 64) {
#pragma unroll
        for (int i = 0; i < 4; ++i) {
            const int ldso = (i * 256 + t) * 8;
            gl2lds16(h + (size_t)arow[i] * HPAD + k0 + kc, &As[ldso]);
            gl2lds16(w2e + (size_t)brow[i] * HPAD + k0 + kc, &Bs[ldso]);
        }
        __syncthreads();
#pragma unroll
        for (int kk = 0; kk < 64; kk += 32) {
            const int pc = (((kk >> 3) + lq) ^ sw) * 8;
            bf16x8 af[4];
#pragma unroll
            for (int mi = 0; mi < 4; ++mi)
                af[mi] = *(const bf16x8*)&As[(wm + mi * 16 + lr) * 64 + pc];
#pragma unroll
            for (int ni = 0; ni < 4; ++ni) {
                bf16x8 bf = *(const bf16x8*)&Bs[(wn + ni * 16 + lr) * 64 + pc];
#pragma unroll
                for (int mi = 0; mi < 4; ++mi)
                    acc[mi][ni] = __builtin_amdgcn_mfma_f32_16x16x32_bf16(af[mi], bf, acc[mi][ni], 0, 0, 0);
            }
        }
        __syncthreads();
    }

    unsigned short* ybase = yh + (size_t)kh * NSLOT * DIM;
#pragma unroll
    for (int mi = 0; mi < 4; ++mi) {
#pragma unroll
        for (int rg = 0; rg < 4; ++rg) {
            const int gm = m0 + wm + mi * 16 + lq * 4 + rg;
            if (gm >= M) continue;
            unsigned short* yrow = ybase + (size_t)(hb + gm) * DIM;
#pragma unroll
            for (int ni = 0; ni < 4; ++ni) {
                const int col = n0 + wn + ni * 16 + lr;
                yrow[col] = f2bf(acc[mi][ni][rg]);
            }
        }
    }
}

// ---------------- combine: out[tok] = w0*(y0[s0]+y1[s0]) + w1*(y0[s1]+y1[s1]) ----------------
__global__ void combine_kernel(const unsigned short* __restrict__ yh,
                               const int* __restrict__ meta,
                               const float* __restrict__ tokw,
                               const int* __restrict__ offs,
                               float* __restrict__ out) {
    const int tok = blockIdx.x;
    const int t = threadIdx.x;                      // 256 threads x 4 floats = 1024
    const int m0 = meta[tok * 2], m1 = meta[tok * 2 + 1];
    const float w0 = tokw[tok * 2], w1 = tokw[tok * 2 + 1];
    const size_t r0 = (size_t)(offs[m0 >> 16] + (m0 & 0xffff)) * DIM;
    const size_t r1 = (size_t)(offs[m1 >> 16] + (m1 & 0xffff)) * DIM;
    const unsigned short* p0 = yh;
    const unsigned short* p1 = yh + (size_t)NSLOT * DIM;
    uint2 a0 = ((const uint2*)(p0 + r0))[t];
    uint2 a1 = ((const uint2*)(p1 + r0))[t];
    uint2 b0 = ((const uint2*)(p0 + r1))[t];
    uint2 b1 = ((const uint2*)(p1 + r1))[t];
    float4 o;
    o.x = w0 * (bf2f(a0.x & 0xffff) + bf2f(a1.x & 0xffff)) + w1 * (bf2f(b0.x & 0xffff) + bf2f(b1.x & 0xffff));
    o.y = w0 * (bf2f(a0.x >> 16)    + bf2f(a1.x >> 16))    + w1 * (bf2f(b0.x >> 16)    + bf2f(b1.x >> 16));
    o.z = w0 * (bf2f(a0.y & 0xffff) + bf2f(a1.y & 0xffff)) + w1 * (bf2f(b0.y & 0xffff) + bf2f(b1.y & 0xffff));
    o.w = w0 * (bf2f(a0.y >> 16)    + bf2f(a1.y >> 16))    + w1 * (bf2f(b0.y >> 16)    + bf2f(b1.y >> 16));
    ((float4*)(out + (size_t)tok * DIM))[t] = o;
}

extern "C" void kernel_launch(void* const* d_in, const int* in_sizes, int n_in,
                              void* d_out, int out_size, void* d_ws, size_t ws_size,
                              hipStream_t stream) {
    const float* x  = (const float*)d_in[0];
    const float* gw = (const float*)d_in[1];
    const float* w1 = (const float*)d_in[2];
    const float* w2 = (const float*)d_in[3];   // dict order: w1, w2, w3
    const float* w3 = (const float*)d_in[4];
    float* out = (float*)d_out;

    char* ws = (char*)d_ws;
    size_t o = 0;
    auto alloc = [&](size_t bytes) -> void* {
        void* p = ws + o;
        o += (bytes + 255) & ~(size_t)255;
        return p;
    };
    unsigned short* xb   = (unsigned short*)alloc((size_t)NTOK * DIM * 2);       // 16.8 MB
    unsigned short* w1b  = (unsigned short*)alloc((size_t)NE * HID * DIM * 2);   // 44.7 MB
    unsigned short* w3b  = (unsigned short*)alloc((size_t)NE * HID * DIM * 2);   // 44.7 MB
    unsigned short* w2b  = (unsigned short*)alloc((size_t)NE * DIM * HPAD * 2);  // 45.1 MB
    unsigned short* hbuf = (unsigned short*)alloc((size_t)NSLOT * HPAD * 2);     // 90.2 MB
    int*   toks   = (int*)alloc((size_t)NE * CAP * 4);
    int*   meta   = (int*)alloc((size_t)NTOK * 2 * 4);
    float* tokw   = (float*)alloc((size_t)NTOK * 2 * 4);
    int*   counts = (int*)alloc(256);
    float* psum   = (float*)alloc(256);
    int*   offs   = (int*)alloc(256);
    int*   blk_e  = (int*)alloc(MAXBLK * 4);
    int*   blk_m0 = (int*)alloc(MAXBLK * 4);
    if (o > ws_size) return;
    // bf16 split-K partials: 2 x 16384 x 1024 x 2 B = 67.1 MB, aliased over
    // xb+w1b+w3b (106.2 MB) -- all three are dead once gemm1 completes, and
    // gemm2 (which writes yh) is stream-ordered after gemm1.
    unsigned short* yh = (unsigned short*)xb;

    convert_w_kernel<<<65696, 256, 0, stream>>>(w1, w3, w2, w1b, w3b, w2b, counts, psum);
    router_kernel<<<2048, 256, 0, stream>>>(x, gw, xb, toks, meta, tokw, counts, psum);
    finalize_kernel<<<1, 64, 0, stream>>>(counts, offs, psum, out + (size_t)NTOK * DIM, blk_e, blk_m0);
    gemm1_kernel<<<dim3(22, MAXBLK, 1), 256, 0, stream>>>(xb, w1b, w3b, hbuf, counts, offs, toks, blk_e, blk_m0);
    gemm2_kernel<<<dim3(8, MAXBLK, 2), 256, 0, stream>>>(hbuf, w2b, yh, counts, offs, blk_e, blk_m0);
    combine_kernel<<<NTOK, 256, 0, stream>>>(yh, meta, tokw, offs, out);
}